// Round 2
// baseline (335.799 us; speedup 1.0000x reference)
//
#include <hip/hip_runtime.h>
#include <hip/hip_bf16.h>

#define N_NODES 50000
#define N_EDGES 800000
#define ETOT    (N_EDGES + N_NODES)   // 850000 with self-loops
#define IN_CH   16
#define HID     32
#define HEADS   4
#define C1      (HEADS * HID)         // 128
#define NEG     0.2f
#define SCAN_B  256

typedef unsigned short u16;
typedef unsigned int   u32;

__device__ __forceinline__ float bf2f(u16 b) {
    return __uint_as_float(((u32)b) << 16);
}

// clamp node index defensively (wrong-but-finite beats OOB crash)
__device__ __forceinline__ int clampn(int v) {
    return v < 0 ? 0 : (v >= N_NODES ? N_NODES - 1 : v);
}

// edge endpoint read, int32 vs int64 layout. which: 0=src, 1=dst. e < N_EDGES.
__device__ __forceinline__ int eidx(const int* ei, int e, int i64, int which) {
    int v = i64 ? ei[2 * (which * N_EDGES + e)] : ei[which * N_EDGES + e];
    return clampn(v);
}

// ---- dtype probes: flags[0]=floats are bf16, flags[1]=edge_index is int64 ----
__global__ void k_probe(const u16* xb, const int* ei32, int* flags) {
    __shared__ int cnt, oddnz;
    int t = threadIdx.x;
    if (t == 0) { cnt = 0; oddnz = 0; }
    __syncthreads();
    int my = 0;
    for (int k = t; k < 256; k += 64) {
        float f = bf2f(xb[k]);
        float a = fabsf(f);
        if (f == 0.0f || (a > 9.5e-7f && a < 1.05e6f)) my++;
    }
    atomicAdd(&cnt, my);
    if (t < 32 && ei32[2 * t + 1] != 0) atomicAdd(&oddnz, 1);
    __syncthreads();
    if (t == 0) {
        flags[0] = (cnt >= 224) ? 1 : 0;   // true bf16 -> ~256 sane; fp32 misread -> ~148
        flags[1] = (oddnz == 0) ? 1 : 0;   // int64: all high words of src[0..31] are 0
    }
}

__device__ __forceinline__ float cvt(const void* src, int i, int bf) {
    return bf ? bf2f(((const u16*)src)[i]) : ((const float*)src)[i];
}

__global__ void k_convert_x(const void* x, float* xf, const int* flags) {
    int i = blockIdx.x * blockDim.x + threadIdx.x;
    if (i >= N_NODES * IN_CH) return;
    xf[i] = cvt(x, i, flags[0]);
}

__global__ void k_convert_small(const void* W1, const void* as1, const void* ad1, const void* b1,
                                const void* W2, const void* a2s, const void* a2d, const void* b2,
                                float* W1f, float* as1f, float* ad1f, float* b1f,
                                float* W2f, float* a2sf, float* a2df, float* b2fp,
                                const int* flags) {
    int i = blockIdx.x * blockDim.x + threadIdx.x;
    int bf = flags[0];
    const void* s; float* d; int o;
    if      (i < 2048) { s = W1;  d = W1f;  o = i; }
    else if (i < 2176) { s = as1; d = as1f; o = i - 2048; }
    else if (i < 2304) { s = ad1; d = ad1f; o = i - 2176; }
    else if (i < 2432) { s = b1;  d = b1f;  o = i - 2304; }
    else if (i < 2688) { s = W2;  d = W2f;  o = i - 2432; }
    else if (i < 2690) { s = a2s; d = a2sf; o = i - 2688; }
    else if (i < 2692) { s = a2d; d = a2df; o = i - 2690; }
    else if (i < 2694) { s = b2;  d = b2fp; o = i - 2692; }
    else return;
    d[o] = cvt(s, o, bf);
}

// ---- h1 = x @ W1, stored bf16 [N,128] ----
__global__ void k_h1(const float* __restrict__ xf, const float* __restrict__ W1f,
                     u16* __restrict__ h1) {
    __shared__ float Ws[IN_CH * C1];
    for (int i = threadIdx.x; i < IN_CH * C1; i += blockDim.x) Ws[i] = W1f[i];
    __syncthreads();
    int idx = blockIdx.x * blockDim.x + threadIdx.x;
    if (idx >= N_NODES * C1) return;
    int n = idx >> 7, c = idx & 127;
    float acc = 0.f;
#pragma unroll
    for (int k = 0; k < IN_CH; k++) acc += xf[n * IN_CH + k] * Ws[k * C1 + c];
    __hip_bfloat16 hb = __float2bfloat16(acc);
    h1[idx] = *(u16*)&hb;
}

// ---- as1[n,h], ad1[n,h] ----
__global__ void k_alpha1(const u16* __restrict__ h1, const float* __restrict__ asf,
                         const float* __restrict__ adf,
                         float* __restrict__ as1, float* __restrict__ ad1) {
    int idx = blockIdx.x * blockDim.x + threadIdx.x;
    if (idx >= N_NODES * HEADS) return;
    int n = idx >> 2, h = idx & 3;
    const u16* hp = h1 + n * C1 + h * HID;
    float s = 0.f, d = 0.f;
#pragma unroll
    for (int c = 0; c < HID; c++) {
        float v = bf2f(hp[c]);
        s += v * asf[h * HID + c];
        d += v * adf[h * HID + c];
    }
    as1[idx] = s;
    ad1[idx] = d;
}

// ---- CSR build: degree histogram, 3-kernel exclusive scan, fill ----
__global__ void k_deg(const int* __restrict__ ei, const int* __restrict__ flags,
                      int* __restrict__ off) {
    int e = blockIdx.x * blockDim.x + threadIdx.x;
    if (e >= ETOT) return;
    int d = (e < N_EDGES) ? eidx(ei, e, flags[1], 1) : (e - N_EDGES);
    atomicAdd(&off[d], 1);
}

__global__ void k_scan1(int* __restrict__ off, int* __restrict__ bsum) {
    __shared__ int s[SCAN_B];
    int t = threadIdx.x, i = blockIdx.x * SCAN_B + t;
    int v = (i < N_NODES) ? off[i] : 0;
    s[t] = v; __syncthreads();
    for (int d = 1; d < SCAN_B; d <<= 1) {
        int add = (t >= d) ? s[t - d] : 0; __syncthreads();
        s[t] += add; __syncthreads();
    }
    if (i < N_NODES) off[i] = s[t] - v;           // exclusive within block
    if (t == SCAN_B - 1) bsum[blockIdx.x] = s[t]; // block total
}

__global__ void k_scan2(int* __restrict__ bsum, int nb) {
    __shared__ int s[SCAN_B];
    int t = threadIdx.x;
    int v = (t < nb) ? bsum[t] : 0;
    s[t] = v; __syncthreads();
    for (int d = 1; d < SCAN_B; d <<= 1) {
        int add = (t >= d) ? s[t - d] : 0; __syncthreads();
        s[t] += add; __syncthreads();
    }
    if (t < nb) bsum[t] = s[t] - v;               // exclusive carry per block
}

__global__ void k_scan3(const int* __restrict__ bsum, int* __restrict__ off,
                        int* __restrict__ cursor) {
    int i = blockIdx.x * SCAN_B + threadIdx.x;
    if (i < N_NODES) {
        int o = off[i] + bsum[blockIdx.x];
        off[i] = o; cursor[i] = o;
    } else if (i == N_NODES) {
        off[i] = ETOT; cursor[i] = ETOT;
    }
}

__global__ void k_fill(const int* __restrict__ ei, const int* __restrict__ flags,
                       int* __restrict__ cursor, int* __restrict__ csr) {
    int e = blockIdx.x * blockDim.x + threadIdx.x;
    if (e >= ETOT) return;
    int i64 = flags[1];
    int s, d;
    if (e < N_EDGES) { s = eidx(ei, e, i64, 0); d = eidx(ei, e, i64, 1); }
    else             { s = d = e - N_EDGES; }
    int slot = atomicAdd(&cursor[d], 1);
    csr[slot] = s;
}

// ---- layer-1 gather + softmax + norm + bias + relu + (out1 @ W2) fused ----
// one wave per dst node; lane l owns channels 2l, 2l+1 (head = l>>4)
__launch_bounds__(256)
__global__ void k_gather1(const int* __restrict__ off, const int* __restrict__ csr,
                          const u32* __restrict__ h1u,
                          const float* __restrict__ as1, const float* __restrict__ ad1,
                          const float* __restrict__ b1f, const float* __restrict__ W2f,
                          const float* __restrict__ a2sf, const float* __restrict__ a2df,
                          float* __restrict__ h2, float* __restrict__ as2,
                          float* __restrict__ ad2) {
    int n = blockIdx.x * 4 + (threadIdx.x >> 6);
    int l = threadIdx.x & 63;
    int hd = l >> 4;
    float adv = ad1[n * 4 + hd];
    int k0 = off[n], k1 = off[n + 1];
    float acc0 = 0.f, acc1 = 0.f, sw = 0.f;
    for (int k = k0; k < k1; k++) {
        int s = csr[k];
        float lg = as1[s * 4 + hd] + adv;
        lg = lg > 0.f ? lg : NEG * lg;
        float w = __expf(lg);
        u32 p = h1u[s * 64 + l];
        acc0 += w * bf2f((u16)(p & 0xFFFF));
        acc1 += w * bf2f((u16)(p >> 16));
        sw += w;
    }
    float inv = 1.0f / sw;                 // sw > 0 guaranteed by self-loop
    float v0 = acc0 * inv + b1f[2 * l];
    float v1 = acc1 * inv + b1f[2 * l + 1];
    v0 = v0 > 0.f ? v0 : 0.f;
    v1 = v1 > 0.f ? v1 : 0.f;
    float p0 = v0 * W2f[4 * l]     + v1 * W2f[4 * l + 2];
    float p1 = v0 * W2f[4 * l + 1] + v1 * W2f[4 * l + 3];
#pragma unroll
    for (int d = 32; d; d >>= 1) { p0 += __shfl_down(p0, d); p1 += __shfl_down(p1, d); }
    if (l == 0) {
        h2[n * 2] = p0; h2[n * 2 + 1] = p1;
        as2[n] = p0 * a2sf[0] + p1 * a2sf[1];
        ad2[n] = p0 * a2df[0] + p1 * a2df[1];
    }
}

// ---- layer-2 gather: one thread per dst node ----
__global__ void k_gather2(const int* __restrict__ off, const int* __restrict__ csr,
                          const float* __restrict__ h2, const float* __restrict__ as2,
                          const float* __restrict__ ad2, const float* __restrict__ b2fp,
                          const int* __restrict__ flags, void* __restrict__ out) {
    int n = blockIdx.x * blockDim.x + threadIdx.x;
    if (n >= N_NODES) return;
    float adv = ad2[n], a0 = 0.f, a1 = 0.f, sw = 0.f;
    int k1 = off[n + 1];
    for (int k = off[n]; k < k1; k++) {
        int s = csr[k];
        float lg = as2[s] + adv;
        lg = lg > 0.f ? lg : NEG * lg;
        float w = __expf(lg);
        a0 += w * h2[s * 2];
        a1 += w * h2[s * 2 + 1];
        sw += w;
    }
    float inv = 1.0f / sw;
    float o0 = a0 * inv + b2fp[0];
    float o1 = a1 * inv + b2fp[1];
    if (flags[0]) {
        ((__hip_bfloat16*)out)[n * 2]     = __float2bfloat16(o0);
        ((__hip_bfloat16*)out)[n * 2 + 1] = __float2bfloat16(o1);
    } else {
        ((float*)out)[n * 2]     = o0;
        ((float*)out)[n * 2 + 1] = o1;
    }
}

extern "C" void kernel_launch(void* const* d_in, const int* in_sizes, int n_in,
                              void* d_out, int out_size, void* d_ws, size_t ws_size,
                              hipStream_t stream) {
    const void* x    = d_in[0];
    const int*  ei   = (const int*)d_in[1];
    const void* W1   = d_in[2];
    const void* a_s1 = d_in[3];
    const void* a_d1 = d_in[4];
    const void* b1   = d_in[5];
    const void* W2   = d_in[6];
    const void* a_s2 = d_in[7];
    const void* a_d2 = d_in[8];
    const void* b2   = d_in[9];

    // ---- ws carve (~22.2 MB total) ----
    char* p = (char*)d_ws;
    int*   flags  = (int*)p;               p += 16;
    int*   off    = (int*)p;               p += (N_NODES + 1) * 4;   // 200004
    int*   cursor = (int*)p;               p += (N_NODES + 1) * 4;
    int*   bsum   = (int*)p;               p += SCAN_B * 4;
    int*   csr    = (int*)p;               p += ETOT * 4;            // 3.4 MB
    float* xf     = (float*)p;             p += N_NODES * IN_CH * 4; // 3.2 MB
    float* W1f    = (float*)p;             p += IN_CH * C1 * 4;
    float* as1f   = (float*)p;             p += C1 * 4;
    float* ad1f   = (float*)p;             p += C1 * 4;
    float* b1f    = (float*)p;             p += C1 * 4;
    float* W2f    = (float*)p;             p += C1 * 2 * 4;
    float* a2sf   = (float*)p;             p += 16;
    float* a2df   = (float*)p;             p += 16;
    float* b2fp   = (float*)p;             p += 16;
    u16*   h1     = (u16*)p;               p += (size_t)N_NODES * C1 * 2; // 12.8 MB
    float* as1    = (float*)p;             p += N_NODES * HEADS * 4;
    float* ad1    = (float*)p;             p += N_NODES * HEADS * 4;
    float* h2     = (float*)p;             p += N_NODES * 2 * 4;
    float* as2    = (float*)p;             p += N_NODES * 4;
    float* ad2    = (float*)p;             p += N_NODES * 4;

    hipMemsetAsync(off, 0, (N_NODES + 1) * sizeof(int), stream);

    const int B = 256;
    const int nbScan = (N_NODES + SCAN_B - 1) / SCAN_B;          // 196
    const int nbScan3 = (N_NODES + 1 + SCAN_B - 1) / SCAN_B;     // 196

    k_probe<<<1, 64, 0, stream>>>((const u16*)x, ei, flags);
    k_convert_x<<<(N_NODES * IN_CH + B - 1) / B, B, 0, stream>>>(x, xf, flags);
    k_convert_small<<<11, B, 0, stream>>>(W1, a_s1, a_d1, b1, W2, a_s2, a_d2, b2,
                                          W1f, as1f, ad1f, b1f, W2f, a2sf, a2df, b2fp,
                                          flags);
    k_h1<<<(N_NODES * C1 + B - 1) / B, B, 0, stream>>>(xf, W1f, h1);
    k_alpha1<<<(N_NODES * HEADS + B - 1) / B, B, 0, stream>>>(h1, as1f, ad1f, as1, ad1);
    k_deg<<<(ETOT + B - 1) / B, B, 0, stream>>>(ei, flags, off);
    k_scan1<<<nbScan, SCAN_B, 0, stream>>>(off, bsum);
    k_scan2<<<1, SCAN_B, 0, stream>>>(bsum, nbScan);
    k_scan3<<<nbScan3, SCAN_B, 0, stream>>>(bsum, off, cursor);
    k_fill<<<(ETOT + B - 1) / B, B, 0, stream>>>(ei, flags, cursor, csr);
    k_gather1<<<N_NODES / 4, 256, 0, stream>>>(off, csr, (const u32*)h1, as1, ad1,
                                               b1f, W2f, a2sf, a2df, h2, as2, ad2);
    k_gather2<<<(N_NODES + B - 1) / B, B, 0, stream>>>(off, csr, h2, as2, ad2, b2fp,
                                                       flags, d_out);
}

// Round 3
// 266.285 us; speedup vs baseline: 1.2611x; 1.2611x over previous
//
#include <hip/hip_runtime.h>
#include <hip/hip_bf16.h>

#define N_NODES 50000
#define N_EDGES 800000
#define ETOT    (N_EDGES + N_NODES)   // 850000 with self-loops
#define IN_CH   16
#define HID     32
#define HEADS   4
#define C1      (HEADS * HID)         // 128
#define NEG     0.2f
#define SCAN_B  256

typedef unsigned short u16;
typedef unsigned int   u32;

__device__ __forceinline__ float bf2f(u16 b) {
    return __uint_as_float(((u32)b) << 16);
}

__device__ __forceinline__ u16 f2bf(float f) {
    __hip_bfloat16 hb = __float2bfloat16(f);
    return *(u16*)&hb;
}

__device__ __forceinline__ int clampn(int v) {
    return v < 0 ? 0 : (v >= N_NODES ? N_NODES - 1 : v);
}

// edge endpoint read, int32 vs int64 layout. which: 0=src, 1=dst. e < N_EDGES.
__device__ __forceinline__ int eidx(const int* ei, int e, int i64, int which) {
    int v = i64 ? ei[2 * (which * N_EDGES + e)] : ei[which * N_EDGES + e];
    return clampn(v);
}

__device__ __forceinline__ float cvt(const void* src, int i, int bf) {
    return bf ? bf2f(((const u16*)src)[i]) : ((const float*)src)[i];
}

// ---- dtype probes: flags[0]=floats are bf16, flags[1]=edge_index is int64 ----
__global__ void k_probe(const u16* xb, const int* ei32, int* flags) {
    __shared__ int cnt, oddnz;
    int t = threadIdx.x;
    if (t == 0) { cnt = 0; oddnz = 0; }
    __syncthreads();
    int my = 0;
    for (int k = t; k < 256; k += 64) {
        float f = bf2f(xb[k]);
        float a = fabsf(f);
        if (f == 0.0f || (a > 9.5e-7f && a < 1.05e6f)) my++;
    }
    atomicAdd(&cnt, my);
    if (t < 32 && ei32[2 * t + 1] != 0) atomicAdd(&oddnz, 1);
    __syncthreads();
    if (t == 0) {
        flags[0] = (cnt >= 224) ? 1 : 0;   // true bf16 -> ~256 sane; fp32 misread -> ~148
        flags[1] = (oddnz == 0) ? 1 : 0;   // int64: all high words of src[0..31] are 0
    }
}

// ---- fused: h1 = x@W1 (bf16-packed), as1/ad1 attention coefficients ----
// block = 256 = 4 waves; one node per wave; lane l owns channels 2l, 2l+1
__launch_bounds__(256)
__global__ void k_h1_fused(const void* __restrict__ x, const void* __restrict__ W1,
                           const void* __restrict__ a_s, const void* __restrict__ a_d,
                           const int* __restrict__ flags,
                           u32* __restrict__ h1u, float* __restrict__ as1,
                           float* __restrict__ ad1) {
    __shared__ float Ws[IN_CH * C1];   // 8 KB
    __shared__ float As[C1], Ad[C1];
    __shared__ float xs[4][IN_CH];
    int bf = flags[0];
    for (int i = threadIdx.x; i < IN_CH * C1 + 2 * C1; i += 256) {
        if (i < IN_CH * C1)           Ws[i] = cvt(W1, i, bf);
        else if (i < IN_CH * C1 + C1) As[i - IN_CH * C1] = cvt(a_s, i - IN_CH * C1, bf);
        else                          Ad[i - IN_CH * C1 - C1] = cvt(a_d, i - IN_CH * C1 - C1, bf);
    }
    int w = threadIdx.x >> 6, l = threadIdx.x & 63;
    int n = blockIdx.x * 4 + w;
    if (l < IN_CH) xs[w][l] = cvt(x, n * IN_CH + l, bf);
    __syncthreads();

    int c0 = 2 * l, c1 = 2 * l + 1;
    float acc0 = 0.f, acc1 = 0.f;
#pragma unroll
    for (int k = 0; k < IN_CH; k++) {
        float xv = xs[w][k];
        acc0 += xv * Ws[k * C1 + c0];
        acc1 += xv * Ws[k * C1 + c1];
    }
    h1u[n * 64 + l] = (u32)f2bf(acc0) | ((u32)f2bf(acc1) << 16);

    float ps = acc0 * As[c0] + acc1 * As[c1];
    float pd = acc0 * Ad[c0] + acc1 * Ad[c1];
#pragma unroll
    for (int m = 8; m; m >>= 1) { ps += __shfl_xor(ps, m); pd += __shfl_xor(pd, m); }
    if ((l & 15) == 0) {
        int hd = l >> 4;
        as1[n * 4 + hd] = ps;
        ad1[n * 4 + hd] = pd;
    }
}

// ---- CSR build: degree histogram, 3-kernel exclusive scan, fill ----
__global__ void k_deg(const int* __restrict__ ei, const int* __restrict__ flags,
                      int* __restrict__ off) {
    int e = blockIdx.x * blockDim.x + threadIdx.x;
    if (e >= ETOT) return;
    int d = (e < N_EDGES) ? eidx(ei, e, flags[1], 1) : (e - N_EDGES);
    atomicAdd(&off[d], 1);
}

__global__ void k_scan1(int* __restrict__ off, int* __restrict__ bsum) {
    __shared__ int s[SCAN_B];
    int t = threadIdx.x, i = blockIdx.x * SCAN_B + t;
    int v = (i < N_NODES) ? off[i] : 0;
    s[t] = v; __syncthreads();
    for (int d = 1; d < SCAN_B; d <<= 1) {
        int add = (t >= d) ? s[t - d] : 0; __syncthreads();
        s[t] += add; __syncthreads();
    }
    if (i < N_NODES) off[i] = s[t] - v;           // exclusive within block
    if (t == SCAN_B - 1) bsum[blockIdx.x] = s[t]; // block total
}

__global__ void k_scan2(int* __restrict__ bsum, int nb) {
    __shared__ int s[SCAN_B];
    int t = threadIdx.x;
    int v = (t < nb) ? bsum[t] : 0;
    s[t] = v; __syncthreads();
    for (int d = 1; d < SCAN_B; d <<= 1) {
        int add = (t >= d) ? s[t - d] : 0; __syncthreads();
        s[t] += add; __syncthreads();
    }
    if (t < nb) bsum[t] = s[t] - v;               // exclusive carry per block
}

__global__ void k_scan3(const int* __restrict__ bsum, int* __restrict__ off,
                        int* __restrict__ cursor) {
    int i = blockIdx.x * SCAN_B + threadIdx.x;
    if (i < N_NODES) {
        int o = off[i] + bsum[blockIdx.x];
        off[i] = o; cursor[i] = o;
    } else if (i == N_NODES) {
        off[i] = ETOT; cursor[i] = ETOT;
    }
}

__global__ void k_fill(const int* __restrict__ ei, const int* __restrict__ flags,
                       int* __restrict__ cursor, int* __restrict__ csr) {
    int e = blockIdx.x * blockDim.x + threadIdx.x;
    if (e >= ETOT) return;
    int i64 = flags[1];
    int s, d;
    if (e < N_EDGES) { s = eidx(ei, e, i64, 0); d = eidx(ei, e, i64, 1); }
    else             { s = d = e - N_EDGES; }
    int slot = atomicAdd(&cursor[d], 1);
    csr[slot] = s;
}

// ---- layer-1 gather + softmax + bias + relu + (out1 @ W2) fused ----
// one wave per dst node; lane l owns channels 2l, 2l+1 (head = l>>4)
// 8-wide manual unroll to keep 8 independent load chains in flight
__launch_bounds__(256)
__global__ void k_gather1(const int* __restrict__ off, const int* __restrict__ csr,
                          const u32* __restrict__ h1u,
                          const float* __restrict__ as1, const float* __restrict__ ad1,
                          const void* __restrict__ b1, const void* __restrict__ W2,
                          const void* __restrict__ a2s, const void* __restrict__ a2d,
                          const int* __restrict__ flags,
                          float* __restrict__ h2, float* __restrict__ as2,
                          float* __restrict__ ad2) {
    int n = blockIdx.x * 4 + (threadIdx.x >> 6);
    int l = threadIdx.x & 63;
    int hd = l >> 4;
    float adv = ad1[n * 4 + hd];
    int k = off[n], k1 = off[n + 1];
    float acc0 = 0.f, acc1 = 0.f, sw = 0.f;

    for (; k + 8 <= k1; k += 8) {
        int s[8]; u32 p[8]; float lg[8];
#pragma unroll
        for (int j = 0; j < 8; j++) s[j] = csr[k + j];
#pragma unroll
        for (int j = 0; j < 8; j++) {
            lg[j] = as1[s[j] * 4 + hd];
            p[j]  = h1u[s[j] * 64 + l];
        }
#pragma unroll
        for (int j = 0; j < 8; j++) {
            float t = lg[j] + adv;
            t = t > 0.f ? t : NEG * t;
            float w = __expf(t);
            sw   += w;
            acc0 += w * bf2f((u16)(p[j] & 0xFFFF));
            acc1 += w * bf2f((u16)(p[j] >> 16));
        }
    }
    for (; k < k1; k++) {
        int s = csr[k];
        float t = as1[s * 4 + hd] + adv;
        t = t > 0.f ? t : NEG * t;
        float w = __expf(t);
        u32 p = h1u[s * 64 + l];
        sw   += w;
        acc0 += w * bf2f((u16)(p & 0xFFFF));
        acc1 += w * bf2f((u16)(p >> 16));
    }

    int bf = flags[0];
    float inv = 1.0f / sw;                 // sw > 0 guaranteed by self-loop
    float v0 = acc0 * inv + cvt(b1, 2 * l, bf);
    float v1 = acc1 * inv + cvt(b1, 2 * l + 1, bf);
    v0 = v0 > 0.f ? v0 : 0.f;
    v1 = v1 > 0.f ? v1 : 0.f;
    float p0 = v0 * cvt(W2, 4 * l,     bf) + v1 * cvt(W2, 4 * l + 2, bf);
    float p1 = v0 * cvt(W2, 4 * l + 1, bf) + v1 * cvt(W2, 4 * l + 3, bf);
#pragma unroll
    for (int d = 32; d; d >>= 1) { p0 += __shfl_down(p0, d); p1 += __shfl_down(p1, d); }
    if (l == 0) {
        h2[n * 2] = p0; h2[n * 2 + 1] = p1;
        as2[n] = p0 * cvt(a2s, 0, bf) + p1 * cvt(a2s, 1, bf);
        ad2[n] = p0 * cvt(a2d, 0, bf) + p1 * cvt(a2d, 1, bf);
    }
}

// ---- layer-2 gather: 16 lanes per dst node, shuffle reduce ----
__launch_bounds__(256)
__global__ void k_gather2(const int* __restrict__ off, const int* __restrict__ csr,
                          const float* __restrict__ h2, const float* __restrict__ as2,
                          const float* __restrict__ ad2, const void* __restrict__ b2,
                          const int* __restrict__ flags, void* __restrict__ out) {
    int n = blockIdx.x * 16 + (threadIdx.x >> 4);
    int g = threadIdx.x & 15;
    float adv = ad2[n], a0 = 0.f, a1 = 0.f, sw = 0.f;
    int k1 = off[n + 1];
    for (int k = off[n] + g; k < k1; k += 16) {
        int s = csr[k];
        float lg = as2[s] + adv;
        lg = lg > 0.f ? lg : NEG * lg;
        float w = __expf(lg);
        float2 hv = ((const float2*)h2)[s];
        a0 += w * hv.x;
        a1 += w * hv.y;
        sw += w;
    }
#pragma unroll
    for (int m = 8; m; m >>= 1) {
        a0 += __shfl_xor(a0, m); a1 += __shfl_xor(a1, m); sw += __shfl_xor(sw, m);
    }
    if (g == 0) {
        int bf = flags[0];
        float inv = 1.0f / sw;
        float o0 = a0 * inv + cvt(b2, 0, bf);
        float o1 = a1 * inv + cvt(b2, 1, bf);
        if (bf) {
            ((u32*)out)[n] = (u32)f2bf(o0) | ((u32)f2bf(o1) << 16);
        } else {
            ((float2*)out)[n] = make_float2(o0, o1);
        }
    }
}

extern "C" void kernel_launch(void* const* d_in, const int* in_sizes, int n_in,
                              void* d_out, int out_size, void* d_ws, size_t ws_size,
                              hipStream_t stream) {
    const void* x    = d_in[0];
    const int*  ei   = (const int*)d_in[1];
    const void* W1   = d_in[2];
    const void* a_s1 = d_in[3];
    const void* a_d1 = d_in[4];
    const void* b1   = d_in[5];
    const void* W2   = d_in[6];
    const void* a_s2 = d_in[7];
    const void* a_d2 = d_in[8];
    const void* b2   = d_in[9];

    // ---- ws carve (~17 MB total) ----
    char* p = (char*)d_ws;
    int*   flags  = (int*)p;               p += 16;
    int*   off    = (int*)p;               p += (N_NODES + 1) * 4;
    int*   cursor = (int*)p;               p += (N_NODES + 1) * 4;
    int*   bsum   = (int*)p;               p += SCAN_B * 4;
    int*   csr    = (int*)p;               p += ETOT * 4;                 // 3.4 MB
    u32*   h1u    = (u32*)p;               p += (size_t)N_NODES * 64 * 4; // 12.8 MB
    float* as1    = (float*)p;             p += N_NODES * HEADS * 4;
    float* ad1    = (float*)p;             p += N_NODES * HEADS * 4;
    float* h2     = (float*)p;             p += N_NODES * 2 * 4;
    float* as2    = (float*)p;             p += N_NODES * 4;
    float* ad2    = (float*)p;             p += N_NODES * 4;

    hipMemsetAsync(off, 0, (N_NODES + 1) * sizeof(int), stream);

    const int B = 256;
    const int nbScan  = (N_NODES + SCAN_B - 1) / SCAN_B;         // 196
    const int nbScan3 = (N_NODES + 1 + SCAN_B - 1) / SCAN_B;

    k_probe<<<1, 64, 0, stream>>>((const u16*)x, ei, flags);
    k_deg<<<(ETOT + B - 1) / B, B, 0, stream>>>(ei, flags, off);
    k_scan1<<<nbScan, SCAN_B, 0, stream>>>(off, bsum);
    k_scan2<<<1, SCAN_B, 0, stream>>>(bsum, nbScan);
    k_scan3<<<nbScan3, SCAN_B, 0, stream>>>(bsum, off, cursor);
    k_fill<<<(ETOT + B - 1) / B, B, 0, stream>>>(ei, flags, cursor, csr);
    k_h1_fused<<<N_NODES / 4, 256, 0, stream>>>(x, W1, a_s1, a_d1, flags, h1u, as1, ad1);
    k_gather1<<<N_NODES / 4, 256, 0, stream>>>(off, csr, h1u, as1, ad1,
                                               b1, W2, a_s2, a_d2, flags, h2, as2, ad2);
    k_gather2<<<(N_NODES + 15) / 16, 256, 0, stream>>>(off, csr, h2, as2, ad2, b2,
                                                       flags, d_out);
}

// Round 4
// 231.652 us; speedup vs baseline: 1.4496x; 1.1495x over previous
//
#include <hip/hip_runtime.h>
#include <hip/hip_bf16.h>

#define N_NODES 50000
#define N_EDGES 800000
#define ETOT    (N_EDGES + N_NODES)   // 850000 with self-loops
#define IN_CH   16
#define HID     32
#define HEADS   4
#define C1      (HEADS * HID)         // 128
#define NEG     0.2f
#define SCAN_B  256

typedef unsigned short u16;
typedef unsigned int   u32;

__device__ __forceinline__ float bf2f(u16 b) {
    return __uint_as_float(((u32)b) << 16);
}

__device__ __forceinline__ u16 f2bf(float f) {
    __hip_bfloat16 hb = __float2bfloat16(f);
    return *(u16*)&hb;
}

__device__ __forceinline__ int clampn(int v) {
    return v < 0 ? 0 : (v >= N_NODES ? N_NODES - 1 : v);
}

// edge endpoint read, int32 vs int64 layout. which: 0=src, 1=dst. e < N_EDGES.
__device__ __forceinline__ int eidx(const int* ei, int e, int i64, int which) {
    int v = i64 ? ei[2 * (which * N_EDGES + e)] : ei[which * N_EDGES + e];
    return clampn(v);
}

__device__ __forceinline__ float cvt(const void* src, int i, int bf) {
    return bf ? bf2f(((const u16*)src)[i]) : ((const float*)src)[i];
}

// ---- dtype probes: flags[0]=floats are bf16, flags[1]=edge_index is int64 ----
__global__ void k_probe(const u16* xb, const int* ei32, int* flags) {
    __shared__ int cnt, oddnz;
    int t = threadIdx.x;
    if (t == 0) { cnt = 0; oddnz = 0; }
    __syncthreads();
    int my = 0;
    for (int k = t; k < 256; k += 64) {
        float f = bf2f(xb[k]);
        float a = fabsf(f);
        if (f == 0.0f || (a > 9.5e-7f && a < 1.05e6f)) my++;
    }
    atomicAdd(&cnt, my);
    if (t < 32 && ei32[2 * t + 1] != 0) atomicAdd(&oddnz, 1);
    __syncthreads();
    if (t == 0) {
        flags[0] = (cnt >= 224) ? 1 : 0;   // true bf16 -> ~256 sane; fp32 misread -> ~148
        flags[1] = (oddnz == 0) ? 1 : 0;   // int64: all high words of src[0..31] are 0
    }
}

// ---- fused: h1 = x@W1 (bf16-packed), as1/ad1 attention coefficients ----
__launch_bounds__(256)
__global__ void k_h1_fused(const void* __restrict__ x, const void* __restrict__ W1,
                           const void* __restrict__ a_s, const void* __restrict__ a_d,
                           const int* __restrict__ flags,
                           u32* __restrict__ h1u, float* __restrict__ as1,
                           float* __restrict__ ad1) {
    __shared__ float Ws[IN_CH * C1];   // 8 KB
    __shared__ float As[C1], Ad[C1];
    __shared__ float xs[4][IN_CH];
    int bf = flags[0];
    for (int i = threadIdx.x; i < IN_CH * C1 + 2 * C1; i += 256) {
        if (i < IN_CH * C1)           Ws[i] = cvt(W1, i, bf);
        else if (i < IN_CH * C1 + C1) As[i - IN_CH * C1] = cvt(a_s, i - IN_CH * C1, bf);
        else                          Ad[i - IN_CH * C1 - C1] = cvt(a_d, i - IN_CH * C1 - C1, bf);
    }
    int w = threadIdx.x >> 6, l = threadIdx.x & 63;
    int n = blockIdx.x * 4 + w;
    if (l < IN_CH) xs[w][l] = cvt(x, n * IN_CH + l, bf);
    __syncthreads();

    int c0 = 2 * l, c1 = 2 * l + 1;
    float acc0 = 0.f, acc1 = 0.f;
#pragma unroll
    for (int k = 0; k < IN_CH; k++) {
        float xv = xs[w][k];
        acc0 += xv * Ws[k * C1 + c0];
        acc1 += xv * Ws[k * C1 + c1];
    }
    h1u[n * 64 + l] = (u32)f2bf(acc0) | ((u32)f2bf(acc1) << 16);

    float ps = acc0 * As[c0] + acc1 * As[c1];
    float pd = acc0 * Ad[c0] + acc1 * Ad[c1];
#pragma unroll
    for (int m = 8; m; m >>= 1) { ps += __shfl_xor(ps, m); pd += __shfl_xor(pd, m); }
    if ((l & 15) == 0) {
        int hd = l >> 4;
        as1[n * 4 + hd] = ps;
        ad1[n * 4 + hd] = pd;
    }
}

// ---- CSR build ----
// k_deg: count degree AND record each edge's rank (atomic return), coalesced.
__global__ void k_deg(const int* __restrict__ ei, const int* __restrict__ flags,
                      int* __restrict__ off, int* __restrict__ rank) {
    int e0 = (blockIdx.x * blockDim.x + threadIdx.x) * 4;
    if (e0 >= ETOT) return;       // ETOT % 4 == 0, quads never straddle
    int i64 = flags[1];
    int d[4];
#pragma unroll
    for (int j = 0; j < 4; j++) {
        int e = e0 + j;
        d[j] = (e < N_EDGES) ? eidx(ei, e, i64, 1) : (e - N_EDGES);
    }
    int r[4];
#pragma unroll
    for (int j = 0; j < 4; j++) r[j] = atomicAdd(&off[d[j]], 1);  // 4 indep chains
    *(int4*)(rank + e0) = make_int4(r[0], r[1], r[2], r[3]);
}

__global__ void k_scan1(int* __restrict__ off, int* __restrict__ bsum) {
    __shared__ int s[SCAN_B];
    int t = threadIdx.x, i = blockIdx.x * SCAN_B + t;
    int v = (i < N_NODES) ? off[i] : 0;
    s[t] = v; __syncthreads();
    for (int d = 1; d < SCAN_B; d <<= 1) {
        int add = (t >= d) ? s[t - d] : 0; __syncthreads();
        s[t] += add; __syncthreads();
    }
    if (i < N_NODES) off[i] = s[t] - v;           // exclusive within block
    if (t == SCAN_B - 1) bsum[blockIdx.x] = s[t]; // block total
}

__global__ void k_scan2(int* __restrict__ bsum, int nb) {
    __shared__ int s[SCAN_B];
    int t = threadIdx.x;
    int v = (t < nb) ? bsum[t] : 0;
    s[t] = v; __syncthreads();
    for (int d = 1; d < SCAN_B; d <<= 1) {
        int add = (t >= d) ? s[t - d] : 0; __syncthreads();
        s[t] += add; __syncthreads();
    }
    if (t < nb) bsum[t] = s[t] - v;               // exclusive carry per block
}

__global__ void k_scan3(const int* __restrict__ bsum, int* __restrict__ off) {
    int i = blockIdx.x * SCAN_B + threadIdx.x;
    if (i < N_NODES)       off[i] += bsum[blockIdx.x];
    else if (i == N_NODES) off[i] = ETOT;
}

// k_fill: atomic-free — slot = off[dst] + rank[e]; pure scattered store.
__global__ void k_fill(const int* __restrict__ ei, const int* __restrict__ flags,
                       const int* __restrict__ off, const int* __restrict__ rank,
                       int* __restrict__ csr) {
    int e0 = (blockIdx.x * blockDim.x + threadIdx.x) * 4;
    if (e0 >= ETOT) return;
    int i64 = flags[1];
    int4 r = *(const int4*)(rank + e0);
    int rr[4] = {r.x, r.y, r.z, r.w};
    int s[4], slot[4];
#pragma unroll
    for (int j = 0; j < 4; j++) {
        int e = e0 + j;
        int src, d;
        if (e < N_EDGES) { src = eidx(ei, e, i64, 0); d = eidx(ei, e, i64, 1); }
        else             { src = d = e - N_EDGES; }
        s[j] = src;
        slot[j] = off[d] + rr[j];
    }
#pragma unroll
    for (int j = 0; j < 4; j++) csr[slot[j]] = s[j];
}

// ---- layer-1 gather + softmax + bias + relu + (out1 @ W2) fused ----
// one wave per dst node; lane l owns channels 2l, 2l+1 (head hd = l>>4).
// Weight dedup: per 8-edge batch, lane l computes the weight for edge (l&7),
// head ((l>>3)&3); consumers fetch via __shfl(wm, 8*hd + j).
__launch_bounds__(256)
__global__ void k_gather1(const int* __restrict__ off, const int* __restrict__ csr,
                          const u32* __restrict__ h1u,
                          const float* __restrict__ as1, const float* __restrict__ ad1,
                          const void* __restrict__ b1, const void* __restrict__ W2,
                          const void* __restrict__ a2s, const void* __restrict__ a2d,
                          const int* __restrict__ flags,
                          float* __restrict__ h2, float* __restrict__ as2,
                          float* __restrict__ ad2) {
    int n = blockIdx.x * 4 + (threadIdx.x >> 6);
    int l = threadIdx.x & 63;
    int hd = l >> 4;                 // my head (channel ownership)
    int jb = l & 7;                  // weight-duty: edge slot
    int hb = (l >> 3) & 3;           // weight-duty: head
    int wbase = 8 * hd;              // lane holding (edge j, my head)'s weight
    float adv  = ad1[n * 4 + hd];    // for tail loop
    float advb = ad1[n * 4 + hb];    // for weight duty
    int k = off[n], k1 = off[n + 1];
    float acc0 = 0.f, acc1 = 0.f, sw = 0.f;

    for (; k + 8 <= k1; k += 8) {
        int se = csr[k + jb];                       // 8 distinct dwords / wave
        float t = as1[se * 4 + hb] + advb;          // 32 distinct dwords / wave
        t = t > 0.f ? t : NEG * t;
        float wm = __expf(t);
#pragma unroll
        for (int j = 0; j < 8; j++) {
            int   sj = __shfl(se, j);               // edge j's src
            float wj = __shfl(wm, wbase + j);       // edge j's weight, my head
            u32 p = h1u[sj * 64 + l];
            sw   += wj;
            acc0 += wj * bf2f((u16)(p & 0xFFFF));
            acc1 += wj * bf2f((u16)(p >> 16));
        }
    }
    for (; k < k1; k++) {
        int s = csr[k];
        float t = as1[s * 4 + hd] + adv;
        t = t > 0.f ? t : NEG * t;
        float w = __expf(t);
        u32 p = h1u[s * 64 + l];
        sw   += w;
        acc0 += w * bf2f((u16)(p & 0xFFFF));
        acc1 += w * bf2f((u16)(p >> 16));
    }

    int bf = flags[0];
    float inv = 1.0f / sw;                 // sw > 0 guaranteed by self-loop
    float v0 = acc0 * inv + cvt(b1, 2 * l, bf);
    float v1 = acc1 * inv + cvt(b1, 2 * l + 1, bf);
    v0 = v0 > 0.f ? v0 : 0.f;
    v1 = v1 > 0.f ? v1 : 0.f;
    float p0 = v0 * cvt(W2, 4 * l,     bf) + v1 * cvt(W2, 4 * l + 2, bf);
    float p1 = v0 * cvt(W2, 4 * l + 1, bf) + v1 * cvt(W2, 4 * l + 3, bf);
#pragma unroll
    for (int d = 32; d; d >>= 1) { p0 += __shfl_down(p0, d); p1 += __shfl_down(p1, d); }
    if (l == 0) {
        h2[n * 2] = p0; h2[n * 2 + 1] = p1;
        as2[n] = p0 * cvt(a2s, 0, bf) + p1 * cvt(a2s, 1, bf);
        ad2[n] = p0 * cvt(a2d, 0, bf) + p1 * cvt(a2d, 1, bf);
    }
}

// ---- layer-2 gather: 16 lanes per dst node, shuffle reduce ----
__launch_bounds__(256)
__global__ void k_gather2(const int* __restrict__ off, const int* __restrict__ csr,
                          const float* __restrict__ h2, const float* __restrict__ as2,
                          const float* __restrict__ ad2, const void* __restrict__ b2,
                          const int* __restrict__ flags, void* __restrict__ out) {
    int n = blockIdx.x * 16 + (threadIdx.x >> 4);
    int g = threadIdx.x & 15;
    float adv = ad2[n], a0 = 0.f, a1 = 0.f, sw = 0.f;
    int k1 = off[n + 1];
    for (int k = off[n] + g; k < k1; k += 16) {
        int s = csr[k];
        float lg = as2[s] + adv;
        lg = lg > 0.f ? lg : NEG * lg;
        float w = __expf(lg);
        float2 hv = ((const float2*)h2)[s];
        a0 += w * hv.x;
        a1 += w * hv.y;
        sw += w;
    }
#pragma unroll
    for (int m = 8; m; m >>= 1) {
        a0 += __shfl_xor(a0, m); a1 += __shfl_xor(a1, m); sw += __shfl_xor(sw, m);
    }
    if (g == 0) {
        int bf = flags[0];
        float inv = 1.0f / sw;
        float o0 = a0 * inv + cvt(b2, 0, bf);
        float o1 = a1 * inv + cvt(b2, 1, bf);
        if (bf) {
            ((u32*)out)[n] = (u32)f2bf(o0) | ((u32)f2bf(o1) << 16);
        } else {
            ((float2*)out)[n] = make_float2(o0, o1);
        }
    }
}

extern "C" void kernel_launch(void* const* d_in, const int* in_sizes, int n_in,
                              void* d_out, int out_size, void* d_ws, size_t ws_size,
                              hipStream_t stream) {
    const void* x    = d_in[0];
    const int*  ei   = (const int*)d_in[1];
    const void* W1   = d_in[2];
    const void* a_s1 = d_in[3];
    const void* a_d1 = d_in[4];
    const void* b1   = d_in[5];
    const void* W2   = d_in[6];
    const void* a_s2 = d_in[7];
    const void* a_d2 = d_in[8];
    const void* b2   = d_in[9];

    // ---- ws carve (~22.2 MB, all segments 16B-aligned) ----
    char* p = (char*)d_ws;
    int*   flags  = (int*)p;               p += 16;
    int*   off    = (int*)p;               p += ((N_NODES + 1) * 4 + 15) & ~15;
    int*   bsum   = (int*)p;               p += SCAN_B * 4;
    int*   rank   = (int*)p;               p += ETOT * 4;                 // 3.4 MB
    int*   csr    = (int*)p;               p += ETOT * 4;                 // 3.4 MB
    u32*   h1u    = (u32*)p;               p += (size_t)N_NODES * 64 * 4; // 12.8 MB
    float* as1    = (float*)p;             p += N_NODES * HEADS * 4;
    float* ad1    = (float*)p;             p += N_NODES * HEADS * 4;
    float* h2     = (float*)p;             p += N_NODES * 2 * 4;
    float* as2    = (float*)p;             p += N_NODES * 4;
    float* ad2    = (float*)p;             p += N_NODES * 4;

    hipMemsetAsync(off, 0, (N_NODES + 1) * sizeof(int), stream);

    const int B = 256;
    const int nbScan  = (N_NODES + SCAN_B - 1) / SCAN_B;           // 196
    const int nbScan3 = (N_NODES + 1 + SCAN_B - 1) / SCAN_B;
    const int nbEdge4 = (ETOT / 4 + B - 1) / B;                    // 831

    k_probe<<<1, 64, 0, stream>>>((const u16*)x, ei, flags);
    k_h1_fused<<<N_NODES / 4, 256, 0, stream>>>(x, W1, a_s1, a_d1, flags, h1u, as1, ad1);
    k_deg<<<nbEdge4, B, 0, stream>>>(ei, flags, off, rank);
    k_scan1<<<nbScan, SCAN_B, 0, stream>>>(off, bsum);
    k_scan2<<<1, SCAN_B, 0, stream>>>(bsum, nbScan);
    k_scan3<<<nbScan3, SCAN_B, 0, stream>>>(bsum, off);
    k_fill<<<nbEdge4, B, 0, stream>>>(ei, flags, off, rank, csr);
    k_gather1<<<N_NODES / 4, 256, 0, stream>>>(off, csr, h1u, as1, ad1,
                                               b1, W2, a_s2, a_d2, flags, h2, as2, ad2);
    k_gather2<<<(N_NODES + 15) / 16, 256, 0, stream>>>(off, csr, h2, as2, ad2, b2,
                                                       flags, d_out);
}

// Round 5
// 225.199 us; speedup vs baseline: 1.4911x; 1.0287x over previous
//
#include <hip/hip_runtime.h>
#include <hip/hip_bf16.h>

#define N_NODES 50000
#define N_EDGES 800000
#define ETOT    (N_EDGES + N_NODES)   // 850000 with self-loops
#define CSRCAP  1600000               // worst-case padded: ETOT + 15*N_NODES
#define IN_CH   16
#define HID     32
#define HEADS   4
#define C1      (HEADS * HID)         // 128
#define NEG     0.2f
#define SCAN_B  256

typedef unsigned short u16;
typedef unsigned int   u32;

__device__ __forceinline__ float bf2f(u16 b) {
    return __uint_as_float(((u32)b) << 16);
}

__device__ __forceinline__ u16 f2bf(float f) {
    __hip_bfloat16 hb = __float2bfloat16(f);
    return *(u16*)&hb;
}

__device__ __forceinline__ int clampn(int v) {
    return v < 0 ? 0 : (v >= N_NODES ? N_NODES - 1 : v);
}

// edge endpoint read, int32 vs int64 layout. which: 0=src, 1=dst. e < N_EDGES.
__device__ __forceinline__ int eidx(const int* ei, int e, int i64, int which) {
    int v = i64 ? ei[2 * (which * N_EDGES + e)] : ei[which * N_EDGES + e];
    return clampn(v);
}

__device__ __forceinline__ float cvt(const void* src, int i, int bf) {
    return bf ? bf2f(((const u16*)src)[i]) : ((const float*)src)[i];
}

// ---- dtype probes: flags[0]=floats are bf16, flags[1]=edge_index is int64 ----
__global__ void k_probe(const u16* xb, const int* ei32, int* flags) {
    __shared__ int cnt, oddnz;
    int t = threadIdx.x;
    if (t == 0) { cnt = 0; oddnz = 0; }
    __syncthreads();
    int my = 0;
    for (int k = t; k < 256; k += 64) {
        float f = bf2f(xb[k]);
        float a = fabsf(f);
        if (f == 0.0f || (a > 9.5e-7f && a < 1.05e6f)) my++;
    }
    atomicAdd(&cnt, my);
    if (t < 32 && ei32[2 * t + 1] != 0) atomicAdd(&oddnz, 1);
    __syncthreads();
    if (t == 0) {
        flags[0] = (cnt >= 224) ? 1 : 0;
        flags[1] = (oddnz == 0) ? 1 : 0;
    }
}

// ---- fused: h1 = x@W1 (bf16-packed), as1/ad1 attention coefficients ----
__launch_bounds__(256)
__global__ void k_h1_fused(const void* __restrict__ x, const void* __restrict__ W1,
                           const void* __restrict__ a_s, const void* __restrict__ a_d,
                           const int* __restrict__ flags,
                           u32* __restrict__ h1u, float* __restrict__ as1,
                           float* __restrict__ ad1) {
    __shared__ float Ws[IN_CH * C1];   // 8 KB
    __shared__ float As[C1], Ad[C1];
    __shared__ float xs[4][IN_CH];
    int bf = flags[0];
    for (int i = threadIdx.x; i < IN_CH * C1 + 2 * C1; i += 256) {
        if (i < IN_CH * C1)           Ws[i] = cvt(W1, i, bf);
        else if (i < IN_CH * C1 + C1) As[i - IN_CH * C1] = cvt(a_s, i - IN_CH * C1, bf);
        else                          Ad[i - IN_CH * C1 - C1] = cvt(a_d, i - IN_CH * C1 - C1, bf);
    }
    int w = threadIdx.x >> 6, l = threadIdx.x & 63;
    int n = blockIdx.x * 4 + w;
    if (l < IN_CH) xs[w][l] = cvt(x, n * IN_CH + l, bf);
    // sentinel node row: weight = exp(-inf) = 0 in gathers
    if (blockIdx.x == 0 && threadIdx.x < 4) as1[N_NODES * 4 + threadIdx.x] = -1e30f;
    __syncthreads();

    int c0 = 2 * l, c1 = 2 * l + 1;
    float acc0 = 0.f, acc1 = 0.f;
#pragma unroll
    for (int k = 0; k < IN_CH; k++) {
        float xv = xs[w][k];
        acc0 += xv * Ws[k * C1 + c0];
        acc1 += xv * Ws[k * C1 + c1];
    }
    h1u[n * 64 + l] = (u32)f2bf(acc0) | ((u32)f2bf(acc1) << 16);

    float ps = acc0 * As[c0] + acc1 * As[c1];
    float pd = acc0 * Ad[c0] + acc1 * Ad[c1];
#pragma unroll
    for (int m = 8; m; m >>= 1) { ps += __shfl_xor(ps, m); pd += __shfl_xor(pd, m); }
    if ((l & 15) == 0) {
        int hd = l >> 4;
        as1[n * 4 + hd] = ps;
        ad1[n * 4 + hd] = pd;
    }
}

// ---- CSR build ----
// k_deg: raw degree histogram AND per-edge rank (atomic return), coalesced.
__global__ void k_deg(const int* __restrict__ ei, const int* __restrict__ flags,
                      int* __restrict__ off, int* __restrict__ rank) {
    int e0 = (blockIdx.x * blockDim.x + threadIdx.x) * 4;
    if (e0 >= ETOT) return;       // ETOT % 4 == 0
    int i64 = flags[1];
    int d[4];
#pragma unroll
    for (int j = 0; j < 4; j++) {
        int e = e0 + j;
        d[j] = (e < N_EDGES) ? eidx(ei, e, i64, 1) : (e - N_EDGES);
    }
    int r[4];
#pragma unroll
    for (int j = 0; j < 4; j++) r[j] = atomicAdd(&off[d[j]], 1);
    *(int4*)(rank + e0) = make_int4(r[0], r[1], r[2], r[3]);
}

// scan over PADDED degrees ((deg+15)&~15), indices 0..N inclusive
__global__ void k_scan1(int* __restrict__ off, int* __restrict__ bsum) {
    __shared__ int s[SCAN_B];
    int t = threadIdx.x, i = blockIdx.x * SCAN_B + t;
    int v = 0;
    if (i < N_NODES) v = (off[i] + 15) & ~15;
    s[t] = v; __syncthreads();
    for (int d = 1; d < SCAN_B; d <<= 1) {
        int add = (t >= d) ? s[t - d] : 0; __syncthreads();
        s[t] += add; __syncthreads();
    }
    if (i <= N_NODES) off[i] = s[t] - v;          // exclusive within block
    if (t == SCAN_B - 1) bsum[blockIdx.x] = s[t]; // block total
}

__global__ void k_scan2(int* __restrict__ bsum, int nb) {
    __shared__ int s[SCAN_B];
    int t = threadIdx.x;
    int v = (t < nb) ? bsum[t] : 0;
    s[t] = v; __syncthreads();
    for (int d = 1; d < SCAN_B; d <<= 1) {
        int add = (t >= d) ? s[t - d] : 0; __syncthreads();
        s[t] += add; __syncthreads();
    }
    if (t < nb) bsum[t] = s[t] - v;               // exclusive carry per block
}

__global__ void k_scan3(const int* __restrict__ bsum, int* __restrict__ off) {
    int i = blockIdx.x * SCAN_B + threadIdx.x;
    if (i <= N_NODES) off[i] += bsum[blockIdx.x];
}

// k_fill: atomic-free — slot = off[dst] + rank[e]. Pad slots stay 0xFFFFFFFF.
__global__ void k_fill(const int* __restrict__ ei, const int* __restrict__ flags,
                       const int* __restrict__ off, const int* __restrict__ rank,
                       u32* __restrict__ csr) {
    int e0 = (blockIdx.x * blockDim.x + threadIdx.x) * 4;
    if (e0 >= ETOT) return;
    int i64 = flags[1];
    int4 r = *(const int4*)(rank + e0);
    int rr[4] = {r.x, r.y, r.z, r.w};
    int s[4], slot[4];
#pragma unroll
    for (int j = 0; j < 4; j++) {
        int e = e0 + j;
        int src, d;
        if (e < N_EDGES) { src = eidx(ei, e, i64, 0); d = eidx(ei, e, i64, 1); }
        else             { src = d = e - N_EDGES; }
        s[j] = src;
        slot[j] = off[d] + rr[j];
    }
#pragma unroll
    for (int j = 0; j < 4; j++) csr[slot[j]] = (u32)s[j];
}

// ---- layer-1 gather: pure 16-edge batches (padded CSR), weight dedup ----
// one wave per dst node; lane l owns channels 2l,2l+1; head hd = l>>4.
// lane l computes the weight for edge (l&15) with its OWN head; consumers
// fetch edge j's weight for head hd from lane hd*16+j.
__launch_bounds__(256)
__global__ void k_gather1(const int* __restrict__ off, const u32* __restrict__ csr,
                          const u32* __restrict__ h1u,
                          const float* __restrict__ as1, const float* __restrict__ ad1,
                          const void* __restrict__ b1, const void* __restrict__ W2,
                          const void* __restrict__ a2s, const void* __restrict__ a2d,
                          const int* __restrict__ flags,
                          float* __restrict__ h2, float* __restrict__ as2,
                          float* __restrict__ ad2) {
    int n = blockIdx.x * 4 + (threadIdx.x >> 6);
    int l = threadIdx.x & 63;
    int hd = l >> 4;
    int jb = l & 15;
    float adv = ad1[n * 4 + hd];
    int k0 = off[n], k1 = off[n + 1];   // k1-k0 multiple of 16, >= 16
    float acc0 = 0.f, acc1 = 0.f, sw = 0.f;

    for (int k = k0; k < k1; k += 16) {
        int se = (int)min(csr[k + jb], (u32)N_NODES);  // sentinel -> node N
        float t = as1[se * 4 + hd] + adv;              // sentinel: -1e30
        t = t > 0.f ? t : NEG * t;
        float wm = __expf(t);                          // sentinel: 0
#pragma unroll
        for (int j = 0; j < 16; j++) {
            int   sj = __shfl(se, j);                  // edge j's src (clamped)
            float wj = __shfl(wm, hd * 16 + j);        // edge j's weight, my head
            u32 p = h1u[sj * 64 + l];
            sw   += wj;
            acc0 += wj * bf2f((u16)(p & 0xFFFF));
            acc1 += wj * bf2f((u16)(p >> 16));
        }
    }

    int bf = flags[0];
    float inv = 1.0f / sw;                 // sw > 0 guaranteed by self-loop
    float v0 = acc0 * inv + cvt(b1, 2 * l, bf);
    float v1 = acc1 * inv + cvt(b1, 2 * l + 1, bf);
    v0 = v0 > 0.f ? v0 : 0.f;
    v1 = v1 > 0.f ? v1 : 0.f;
    float p0 = v0 * cvt(W2, 4 * l,     bf) + v1 * cvt(W2, 4 * l + 2, bf);
    float p1 = v0 * cvt(W2, 4 * l + 1, bf) + v1 * cvt(W2, 4 * l + 3, bf);
#pragma unroll
    for (int d = 32; d; d >>= 1) { p0 += __shfl_down(p0, d); p1 += __shfl_down(p1, d); }
    if (l == 0) {
        h2[n * 2] = p0; h2[n * 2 + 1] = p1;
        as2[n] = p0 * cvt(a2s, 0, bf) + p1 * cvt(a2s, 1, bf);
        ad2[n] = p0 * cvt(a2d, 0, bf) + p1 * cvt(a2d, 1, bf);
        if (n == 0) as2[N_NODES] = -1e30f;   // sentinel for gather2
    }
}

// ---- layer-2 gather: 16 lanes per dst node, shuffle reduce, sentinel-safe ----
__launch_bounds__(256)
__global__ void k_gather2(const int* __restrict__ off, const u32* __restrict__ csr,
                          const float* __restrict__ h2, const float* __restrict__ as2,
                          const float* __restrict__ ad2, const void* __restrict__ b2,
                          const int* __restrict__ flags, void* __restrict__ out) {
    int n = blockIdx.x * 16 + (threadIdx.x >> 4);
    int g = threadIdx.x & 15;
    float adv = ad2[n], a0 = 0.f, a1 = 0.f, sw = 0.f;
    int k1 = off[n + 1];
    for (int k = off[n] + g; k < k1; k += 16) {
        int s = (int)min(csr[k], (u32)N_NODES);
        float lg = as2[s] + adv;
        lg = lg > 0.f ? lg : NEG * lg;
        float w = __expf(lg);            // sentinel: 0
        float2 hv = ((const float2*)h2)[s];
        a0 += w * hv.x;
        a1 += w * hv.y;
        sw += w;
    }
#pragma unroll
    for (int m = 8; m; m >>= 1) {
        a0 += __shfl_xor(a0, m); a1 += __shfl_xor(a1, m); sw += __shfl_xor(sw, m);
    }
    if (g == 0) {
        int bf = flags[0];
        float inv = 1.0f / sw;
        float o0 = a0 * inv + cvt(b2, 0, bf);
        float o1 = a1 * inv + cvt(b2, 1, bf);
        if (bf) {
            ((u32*)out)[n] = (u32)f2bf(o0) | ((u32)f2bf(o1) << 16);
        } else {
            ((float2*)out)[n] = make_float2(o0, o1);
        }
    }
}

extern "C" void kernel_launch(void* const* d_in, const int* in_sizes, int n_in,
                              void* d_out, int out_size, void* d_ws, size_t ws_size,
                              hipStream_t stream) {
    const void* x    = d_in[0];
    const int*  ei   = (const int*)d_in[1];
    const void* W1   = d_in[2];
    const void* a_s1 = d_in[3];
    const void* a_d1 = d_in[4];
    const void* b1   = d_in[5];
    const void* W2   = d_in[6];
    const void* a_s2 = d_in[7];
    const void* a_d2 = d_in[8];
    const void* b2   = d_in[9];

    // ---- ws carve (~21.9 MB; rank aliases h1u — rank dead before h1_fused) ----
    char* p = (char*)d_ws;
    int*   flags  = (int*)p;               p += 16;
    int*   off    = (int*)p;               p += ((N_NODES + 1) * 4 + 15) & ~15;
    int*   bsum   = (int*)p;               p += SCAN_B * 4;
    u32*   csr    = (u32*)p;               p += (size_t)CSRCAP * 4;          // 6.4 MB
    char*  region = p;                                                        // alias zone
    int*   rank   = (int*)region;          // ETOT*4 = 3.4 MB   (dead after k_fill)
    u32*   h1u    = (u32*)region;          p += (size_t)(N_NODES + 1) * 64 * 4; // 12.8 MB
    float* as1    = (float*)p;             p += (N_NODES + 1) * HEADS * 4;
    float* ad1    = (float*)p;             p += N_NODES * HEADS * 4;
    float* h2     = (float*)p;             p += (N_NODES + 1) * 2 * 4;
    float* as2    = (float*)p;             p += (N_NODES + 1) * 4;
    float* ad2    = (float*)p;             p += N_NODES * 4;

    hipMemsetAsync(off, 0, (N_NODES + 1) * sizeof(int), stream);
    hipMemsetAsync(csr, 0xFF, (size_t)CSRCAP * 4, stream);   // sentinel pads

    const int B = 256;
    const int nbScan  = (N_NODES + SCAN_B) / SCAN_B;               // 196 (covers 0..N)
    const int nbEdge4 = (ETOT / 4 + B - 1) / B;                    // 831

    k_probe<<<1, 64, 0, stream>>>((const u16*)x, ei, flags);
    k_deg<<<nbEdge4, B, 0, stream>>>(ei, flags, off, rank);
    k_scan1<<<nbScan, SCAN_B, 0, stream>>>(off, bsum);
    k_scan2<<<1, SCAN_B, 0, stream>>>(bsum, nbScan);
    k_scan3<<<nbScan, SCAN_B, 0, stream>>>(bsum, off);
    k_fill<<<nbEdge4, B, 0, stream>>>(ei, flags, off, rank, csr);
    k_h1_fused<<<N_NODES / 4, 256, 0, stream>>>(x, W1, a_s1, a_d1, flags, h1u, as1, ad1);
    k_gather1<<<N_NODES / 4, 256, 0, stream>>>(off, csr, h1u, as1, ad1,
                                               b1, W2, a_s2, a_d2, flags, h2, as2, ad2);
    k_gather2<<<(N_NODES + 15) / 16, 256, 0, stream>>>(off, csr, h2, as2, ad2, b2,
                                                       flags, d_out);
}